// Round 1
// baseline (488.820 us; speedup 1.0000x reference)
//
#include <hip/hip_runtime.h>

// TransformerWithLocalAttention: B=8, S=4096, D=512, BLOCK=64, window=3 blocks, FF=2048
// Pipeline (all bf16 MFMA, f32 accum):
//  cast x -> bf16 | transpose-cast weights -> [N][K] bf16 | QKV fused GEMM (N=1536)
//  V transpose -> [B][D][S] | local attention (MFMA + wave-parallel softmax)
//  LN1(x+a) -> bf16 | FFN1 GEMM+ReLU | FFN2 GEMM -> f32 d_out | LN2 in-place

typedef __bf16 bf16;
typedef __bf16 bf16x8 __attribute__((ext_vector_type(8)));
typedef float  f32x4  __attribute__((ext_vector_type(4)));

#define DEV __device__ __forceinline__

DEV void gload_lds16(const void* g, void* lds) {
  __builtin_amdgcn_global_load_lds(
      (const __attribute__((address_space(1))) void*)g,
      (__attribute__((address_space(3))) void*)lds, 16, 0, 0);
}

// ---------------- elementwise cast x -> bf16 ----------------
__global__ __launch_bounds__(256) void cast_to_bf16(const float* __restrict__ in,
                                                    bf16* __restrict__ out, int n8) {
  int i = blockIdx.x * 256 + threadIdx.x;
  if (i >= n8) return;
  float4 a0 = ((const float4*)in)[i * 2];
  float4 a1 = ((const float4*)in)[i * 2 + 1];
  bf16x8 o;
  o[0] = (bf16)a0.x; o[1] = (bf16)a0.y; o[2] = (bf16)a0.z; o[3] = (bf16)a0.w;
  o[4] = (bf16)a1.x; o[5] = (bf16)a1.y; o[6] = (bf16)a1.z; o[7] = (bf16)a1.w;
  ((bf16x8*)out)[i] = o;
}

// ---------------- W [K][N] f32 -> Wt [N][K] bf16 (LDS-tiled) ----------------
__global__ __launch_bounds__(256) void transpose_cast(const float* __restrict__ W,
                                                      bf16* __restrict__ Wt, int K, int N) {
  __shared__ bf16 tile[64][66];
  const int n0 = blockIdx.x * 64, k0 = blockIdx.y * 64;
  const int t = threadIdx.x;
#pragma unroll
  for (int it = 0; it < 16; ++it) {
    int c = it * 256 + t;
    int kr = c >> 6, nc = c & 63;
    tile[nc][kr] = (bf16)W[(size_t)(k0 + kr) * N + n0 + nc];
  }
  __syncthreads();
#pragma unroll
  for (int it = 0; it < 2; ++it) {
    int c = it * 256 + t;
    int nr = c >> 3, kg = (c & 7) * 8;
    bf16x8 v;
#pragma unroll
    for (int e = 0; e < 8; ++e) v[e] = tile[nr][kg + e];
    *(bf16x8*)(Wt + (size_t)(n0 + nr) * K + k0 + kg) = v;
  }
}

__global__ __launch_bounds__(256) void concat_bias(const float* __restrict__ bq,
                                                   const float* __restrict__ bk,
                                                   const float* __restrict__ bv,
                                                   float* __restrict__ o) {
  int i = blockIdx.x * 256 + threadIdx.x;
  if (i < 512) o[i] = bq[i];
  else if (i < 1024) o[i] = bk[i - 512];
  else if (i < 1536) o[i] = bv[i - 1024];
}

// ---------------- GEMM: C[M][N] = A[M][K] @ Bt[N][K]^T + bias ----------------
// 128x128 tile, BK=32, 4 waves of 64x64, global_load_lds staging, 2-phase dbuf.
template <int RELU, int F32OUT>
__global__ __launch_bounds__(256, 2)
void gemm_bt(const bf16* __restrict__ A, const bf16* __restrict__ Bt,
             const float* __restrict__ bias, void* __restrict__ Cout,
             int M, int N, int K) {
  __shared__ bf16 As[2][128][32];
  __shared__ bf16 Bs[2][128][32];
  const int t = threadIdx.x;
  const int w = t >> 6, l = t & 63;
  const int lr = l & 15, lg = l >> 4;
  const int m0 = blockIdx.x * 128, n0 = blockIdx.y * 128;
  const int wr = (w >> 1) * 64, wc = (w & 1) * 64;

  f32x4 acc[4][4];
#pragma unroll
  for (int i = 0; i < 4; ++i)
#pragma unroll
    for (int j = 0; j < 4; ++j) acc[i][j] = f32x4{0.f, 0.f, 0.f, 0.f};

  const int row_a = t >> 2;
  const int cg = (t & 3) * 8;

  auto stage = [&](int buf, int k0) {
#pragma unroll
    for (int r = 0; r < 2; ++r) {
      gload_lds16(A + (size_t)(m0 + r * 64 + row_a) * K + (k0 + cg),
                  &As[buf][0][0] + (r * 256 + w * 64) * 8);
      gload_lds16(Bt + (size_t)(n0 + r * 64 + row_a) * K + (k0 + cg),
                  &Bs[buf][0][0] + (r * 256 + w * 64) * 8);
    }
  };

  const int nk = K >> 5;
  stage(0, 0);
  asm volatile("s_waitcnt vmcnt(0)" ::: "memory");
  __syncthreads();
  int buf = 0;
  for (int kt = 0; kt < nk; ++kt) {
    if (kt + 1 < nk) stage(buf ^ 1, (kt + 1) << 5);
    bf16x8 af[4], bfr[4];
#pragma unroll
    for (int i = 0; i < 4; ++i) af[i] = *(const bf16x8*)&As[buf][wr + i * 16 + lr][lg * 8];
#pragma unroll
    for (int j = 0; j < 4; ++j) bfr[j] = *(const bf16x8*)&Bs[buf][wc + j * 16 + lr][lg * 8];
#pragma unroll
    for (int i = 0; i < 4; ++i)
#pragma unroll
      for (int j = 0; j < 4; ++j)
        acc[i][j] = __builtin_amdgcn_mfma_f32_16x16x32_bf16(af[i], bfr[j], acc[i][j], 0, 0, 0);
    asm volatile("s_waitcnt vmcnt(0)" ::: "memory");
    __syncthreads();
    buf ^= 1;
  }

#pragma unroll
  for (int j = 0; j < 4; ++j) {
    const int col = n0 + wc + j * 16 + lr;
    const float bv = bias[col];
#pragma unroll
    for (int i = 0; i < 4; ++i)
#pragma unroll
      for (int rg = 0; rg < 4; ++rg) {
        const int row = m0 + wr + i * 16 + lg * 4 + rg;
        float v = acc[i][j][rg] + bv;
        if (RELU) v = fmaxf(v, 0.f);
        if (F32OUT) ((float*)Cout)[(size_t)row * N + col] = v;
        else        ((bf16*)Cout)[(size_t)row * N + col] = (bf16)v;
      }
  }
}

// ---------------- V slice of qkv -> vt [B][512][4096] bf16 ----------------
__global__ __launch_bounds__(256) void transpose_v(const bf16* __restrict__ qkv,
                                                   bf16* __restrict__ vt) {
  __shared__ bf16 tile[64][66];
  const int s0 = blockIdx.x * 64, d0 = blockIdx.y * 64, b = blockIdx.z;
  const int t = threadIdx.x;
#pragma unroll
  for (int it = 0; it < 2; ++it) {
    int c = it * 256 + t;
    int r = c >> 3, g = (c & 7) * 8;
    bf16x8 v = *(const bf16x8*)(qkv + ((size_t)b * 4096 + s0 + r) * 1536 + 1024 + d0 + g);
#pragma unroll
    for (int e = 0; e < 8; ++e) tile[g + e][r] = v[e];
  }
  __syncthreads();
#pragma unroll
  for (int it = 0; it < 2; ++it) {
    int c = it * 256 + t;
    int dr = c >> 3, sg = (c & 7) * 8;
    bf16x8 v;
#pragma unroll
    for (int e = 0; e < 8; ++e) v[e] = tile[dr][sg + e];
    *(bf16x8*)(vt + ((size_t)b * 512 + d0 + dr) * 4096 + s0 + sg) = v;
  }
}

// ---------------- local attention ----------------
// grid (64, 8): query block qb, batch b. 4 waves x 16 query rows.
__global__ __launch_bounds__(256, 2)
void attn_local(const bf16* __restrict__ qkv, const bf16* __restrict__ vt,
                bf16* __restrict__ aout) {
  __shared__ bf16 P[4][16][200];
  const int qb = blockIdx.x, b = blockIdx.y;
  const int t = threadIdx.x, w = t >> 6, l = t & 63;
  const int lr = l & 15, lg = l >> 4;
  const int jlo = (qb == 0) ? 1 : 0;
  const int jhi = (qb == 63) ? 2 : 3;
  const size_t qrow = (size_t)b * 4096 + qb * 64 + w * 16;
  const bf16* qp = qkv + (qrow + lr) * 1536 + lg * 8;

  f32x4 S[3][4];
#pragma unroll
  for (int j = 0; j < 3; ++j)
#pragma unroll
    for (int n = 0; n < 4; ++n) S[j][n] = f32x4{0.f, 0.f, 0.f, 0.f};

  for (int kk = 0; kk < 16; ++kk) {
    bf16x8 aq = *(const bf16x8*)(qp + kk * 32);
#pragma unroll
    for (int j = 0; j < 3; ++j) {
      if (j < jlo || j >= jhi) continue;
      const bf16* kp = qkv + ((size_t)b * 4096 + (qb - 1 + j) * 64) * 1536 + 512;
#pragma unroll
      for (int n = 0; n < 4; ++n) {
        bf16x8 bk = *(const bf16x8*)(kp + (size_t)(n * 16 + lr) * 1536 + kk * 32 + lg * 8);
        S[j][n] = __builtin_amdgcn_mfma_f32_16x16x32_bf16(aq, bk, S[j][n], 0, 0, 0);
      }
    }
  }

  const float scale = 0.044194173824159216f;  // 1/sqrt(512)
  float mx[4] = {-3e38f, -3e38f, -3e38f, -3e38f};
#pragma unroll
  for (int j = 0; j < 3; ++j) {
    if (j < jlo || j >= jhi) continue;
#pragma unroll
    for (int n = 0; n < 4; ++n)
#pragma unroll
      for (int i = 0; i < 4; ++i) mx[i] = fmaxf(mx[i], S[j][n][i]);
  }
#pragma unroll
  for (int i = 0; i < 4; ++i) {
    mx[i] = fmaxf(mx[i], __shfl_xor(mx[i], 1));
    mx[i] = fmaxf(mx[i], __shfl_xor(mx[i], 2));
    mx[i] = fmaxf(mx[i], __shfl_xor(mx[i], 4));
    mx[i] = fmaxf(mx[i], __shfl_xor(mx[i], 8));
  }
  float sm[4] = {0.f, 0.f, 0.f, 0.f};
#pragma unroll
  for (int j = 0; j < 3; ++j) {
    if (j < jlo || j >= jhi) continue;
#pragma unroll
    for (int n = 0; n < 4; ++n)
#pragma unroll
      for (int i = 0; i < 4; ++i) {
        float p = __expf((S[j][n][i] - mx[i]) * scale);
        S[j][n][i] = p;
        sm[i] += p;
      }
  }
#pragma unroll
  for (int i = 0; i < 4; ++i) {
    sm[i] += __shfl_xor(sm[i], 1);
    sm[i] += __shfl_xor(sm[i], 2);
    sm[i] += __shfl_xor(sm[i], 4);
    sm[i] += __shfl_xor(sm[i], 8);
  }
#pragma unroll
  for (int j = 0; j < 3; ++j) {
    if (j < jlo || j >= jhi) continue;
#pragma unroll
    for (int n = 0; n < 4; ++n)
#pragma unroll
      for (int i = 0; i < 4; ++i)
        P[w][lg * 4 + i][j * 64 + n * 16 + lr] = (bf16)S[j][n][i];
  }
  float rinv[4];
#pragma unroll
  for (int i = 0; i < 4; ++i) rinv[i] = 1.f / sm[i];

  const bf16* vtb = vt + (size_t)b * 512 * 4096;
  const long scol = (long)qb * 64 - 64;

#pragma unroll
  for (int ch = 0; ch < 4; ++ch) {
    f32x4 O[8];
#pragma unroll
    for (int n = 0; n < 8; ++n) O[n] = f32x4{0.f, 0.f, 0.f, 0.f};
#pragma unroll
    for (int j = 0; j < 3; ++j) {
      if (j < jlo || j >= jhi) continue;
#pragma unroll
      for (int k2 = 0; k2 < 2; ++k2) {
        bf16x8 ap = *(const bf16x8*)&P[w][lr][j * 64 + k2 * 32 + lg * 8];
#pragma unroll
        for (int n = 0; n < 8; ++n) {
          const bf16* vp = vtb + (long)(ch * 128 + n * 16 + lr) * 4096 +
                           (scol + j * 64 + k2 * 32 + lg * 8);
          bf16x8 bv = *(const bf16x8*)vp;
          O[n] = __builtin_amdgcn_mfma_f32_16x16x32_bf16(ap, bv, O[n], 0, 0, 0);
        }
      }
    }
#pragma unroll
    for (int n = 0; n < 8; ++n)
#pragma unroll
      for (int rg = 0; rg < 4; ++rg) {
        size_t row = qrow + lg * 4 + rg;
        aout[row * 512 + ch * 128 + n * 16 + lr] = (bf16)(O[n][rg] * rinv[rg]);
      }
  }
}

// ---------------- LN1: out1 = LN(x + a) -> bf16 ----------------
__global__ __launch_bounds__(256) void ln_res1(const float* __restrict__ x,
                                               const bf16* __restrict__ a,
                                               const float* __restrict__ g,
                                               const float* __restrict__ be,
                                               bf16* __restrict__ out) {
  const int t = threadIdx.x, w = t >> 6, l = t & 63;
  const size_t row = (size_t)blockIdx.x * 4 + w;
  const float* xp = x + row * 512 + l * 8;
  float4 x0 = ((const float4*)xp)[0];
  float4 x1 = ((const float4*)xp)[1];
  bf16x8 av = *(const bf16x8*)(a + row * 512 + l * 8);
  float s[8] = {x0.x + (float)av[0], x0.y + (float)av[1], x0.z + (float)av[2], x0.w + (float)av[3],
                x1.x + (float)av[4], x1.y + (float)av[5], x1.z + (float)av[6], x1.w + (float)av[7]};
  float sum = 0.f;
#pragma unroll
  for (int i = 0; i < 8; ++i) sum += s[i];
#pragma unroll
  for (int m = 1; m <= 32; m <<= 1) sum += __shfl_xor(sum, m);
  const float mean = sum * (1.f / 512.f);
  float vs = 0.f;
#pragma unroll
  for (int i = 0; i < 8; ++i) { float d = s[i] - mean; vs += d * d; }
#pragma unroll
  for (int m = 1; m <= 32; m <<= 1) vs += __shfl_xor(vs, m);
  const float r = rsqrtf(vs * (1.f / 512.f) + 1e-6f);
  float4 g0 = ((const float4*)(g + l * 8))[0], g1 = ((const float4*)(g + l * 8))[1];
  float4 b0 = ((const float4*)(be + l * 8))[0], b1 = ((const float4*)(be + l * 8))[1];
  bf16x8 o;
  o[0] = (bf16)(g0.x * (s[0] - mean) * r + b0.x);
  o[1] = (bf16)(g0.y * (s[1] - mean) * r + b0.y);
  o[2] = (bf16)(g0.z * (s[2] - mean) * r + b0.z);
  o[3] = (bf16)(g0.w * (s[3] - mean) * r + b0.w);
  o[4] = (bf16)(g1.x * (s[4] - mean) * r + b1.x);
  o[5] = (bf16)(g1.y * (s[5] - mean) * r + b1.y);
  o[6] = (bf16)(g1.z * (s[6] - mean) * r + b1.z);
  o[7] = (bf16)(g1.w * (s[7] - mean) * r + b1.w);
  *(bf16x8*)(out + row * 512 + l * 8) = o;
}

// ---------------- LN2: out = LN(out1 + y), y in d_out (f32), in-place ----------------
__global__ __launch_bounds__(256) void ln_res2(const bf16* __restrict__ o1,
                                               float* __restrict__ y,
                                               const float* __restrict__ g,
                                               const float* __restrict__ be) {
  const int t = threadIdx.x, w = t >> 6, l = t & 63;
  const size_t row = (size_t)blockIdx.x * 4 + w;
  float* yp = y + row * 512 + l * 8;
  float4 y0 = ((const float4*)yp)[0];
  float4 y1 = ((const float4*)yp)[1];
  bf16x8 ov = *(const bf16x8*)(o1 + row * 512 + l * 8);
  float s[8] = {y0.x + (float)ov[0], y0.y + (float)ov[1], y0.z + (float)ov[2], y0.w + (float)ov[3],
                y1.x + (float)ov[4], y1.y + (float)ov[5], y1.z + (float)ov[6], y1.w + (float)ov[7]};
  float sum = 0.f;
#pragma unroll
  for (int i = 0; i < 8; ++i) sum += s[i];
#pragma unroll
  for (int m = 1; m <= 32; m <<= 1) sum += __shfl_xor(sum, m);
  const float mean = sum * (1.f / 512.f);
  float vs = 0.f;
#pragma unroll
  for (int i = 0; i < 8; ++i) { float d = s[i] - mean; vs += d * d; }
#pragma unroll
  for (int m = 1; m <= 32; m <<= 1) vs += __shfl_xor(vs, m);
  const float r = rsqrtf(vs * (1.f / 512.f) + 1e-6f);
  float4 g0 = ((const float4*)(g + l * 8))[0], g1 = ((const float4*)(g + l * 8))[1];
  float4 b0 = ((const float4*)(be + l * 8))[0], b1 = ((const float4*)(be + l * 8))[1];
  float4 r0, r1;
  r0.x = g0.x * (s[0] - mean) * r + b0.x;
  r0.y = g0.y * (s[1] - mean) * r + b0.y;
  r0.z = g0.z * (s[2] - mean) * r + b0.z;
  r0.w = g0.w * (s[3] - mean) * r + b0.w;
  r1.x = g1.x * (s[4] - mean) * r + b1.x;
  r1.y = g1.y * (s[5] - mean) * r + b1.y;
  r1.z = g1.z * (s[6] - mean) * r + b1.z;
  r1.w = g1.w * (s[7] - mean) * r + b1.w;
  ((float4*)yp)[0] = r0;
  ((float4*)yp)[1] = r1;
}

extern "C" void kernel_launch(void* const* d_in, const int* in_sizes, int n_in,
                              void* d_out, int out_size, void* d_ws, size_t ws_size,
                              hipStream_t stream) {
  const float* x   = (const float*)d_in[0];
  const float* Wq  = (const float*)d_in[1];
  const float* bq  = (const float*)d_in[2];
  const float* Wk  = (const float*)d_in[3];
  const float* bk  = (const float*)d_in[4];
  const float* Wv  = (const float*)d_in[5];
  const float* bv  = (const float*)d_in[6];
  const float* W1  = (const float*)d_in[7];
  const float* b1  = (const float*)d_in[8];
  const float* W2  = (const float*)d_in[9];
  const float* b2  = (const float*)d_in[10];
  const float* g1  = (const float*)d_in[11];
  const float* be1 = (const float*)d_in[12];
  const float* g2  = (const float*)d_in[13];
  const float* be2 = (const float*)d_in[14];
  float* out = (float*)d_out;

  char* ws = (char*)d_ws;
  // layout (bytes):
  bf16*  WqkvT = (bf16*)(ws + 0);          // [1536][512]      1,572,864
  bf16*  W1T   = (bf16*)(ws + 1572864);    // [2048][512]      2,097,152
  bf16*  W2T   = (bf16*)(ws + 3670016);    // [512][2048]      2,097,152
  float* bqkv  = (float*)(ws + 5767168);   // [1536]           6,144
  bf16*  xb    = (bf16*)(ws + 6291456);    // [32768][512]     33,554,432  (reused as attn out)
  bf16*  out1  = (bf16*)(ws + 39845888);   // [32768][512]     33,554,432
  bf16*  qkv   = (bf16*)(ws + 73400320);   // [32768][1536]    100,663,296 (reused as h [32768][2048])
  bf16*  vtb   = (bf16*)(ws + 174063616);  // [8][512][4096]   33,554,432  -> end 207,618,048
  bf16*  a_    = xb;
  bf16*  h     = qkv;

  cast_to_bf16<<<8192, 256, 0, stream>>>(x, xb, 2097152);
  transpose_cast<<<dim3(8, 8), 256, 0, stream>>>(Wq, WqkvT, 512, 512);
  transpose_cast<<<dim3(8, 8), 256, 0, stream>>>(Wk, WqkvT + 262144, 512, 512);
  transpose_cast<<<dim3(8, 8), 256, 0, stream>>>(Wv, WqkvT + 524288, 512, 512);
  transpose_cast<<<dim3(32, 8), 256, 0, stream>>>(W1, W1T, 512, 2048);
  transpose_cast<<<dim3(8, 32), 256, 0, stream>>>(W2, W2T, 2048, 512);
  concat_bias<<<6, 256, 0, stream>>>(bq, bk, bv, bqkv);

  gemm_bt<0, 0><<<dim3(256, 12), 256, 0, stream>>>(xb, WqkvT, bqkv, qkv, 32768, 1536, 512);
  transpose_v<<<dim3(64, 8, 8), 256, 0, stream>>>(qkv, vtb);
  attn_local<<<dim3(64, 8), 256, 0, stream>>>(qkv, vtb, a_);
  ln_res1<<<8192, 256, 0, stream>>>(x, a_, g1, be1, out1);
  gemm_bt<1, 0><<<dim3(256, 16), 256, 0, stream>>>(out1, W1T, b1, h, 32768, 2048, 512);
  gemm_bt<0, 1><<<dim3(256, 4), 256, 0, stream>>>(h, W2T, b2, out, 32768, 512, 2048);
  ln_res2<<<8192, 256, 0, stream>>>(out1, out, g2, be2);
}

// Round 3
// 429.899 us; speedup vs baseline: 1.1371x; 1.1371x over previous
//
#include <hip/hip_runtime.h>

// TransformerWithLocalAttention: B=8, S=4096, D=512, BLOCK=64, window=3 blocks, FF=2048
// Round 3: fix R2's LDS race. Stage stream ran 7 half-tiles ahead -> tile t+2
// landed in the buffer tile t was still reading. Now: stage ONLY tile t+1
// (2 half-tiles at q=0, 2 at q=1), drain vmcnt(0) at q=3 before the boundary
// barrier. Keeps 4-phase interleave, T2 both-sides XOR swizzle, T5 setprio,
// T1 XCD swizzle, LDS-staged coalesced bf16 C-write.

typedef __bf16 bf16;
typedef __bf16 bf16x8 __attribute__((ext_vector_type(8)));
typedef float  f32x4  __attribute__((ext_vector_type(4)));

#define DEV __device__ __forceinline__

#define BAR()  do { asm volatile("" ::: "memory"); __builtin_amdgcn_s_barrier(); asm volatile("" ::: "memory"); } while (0)
#define WAITV0() asm volatile("s_waitcnt vmcnt(0)" ::: "memory")
#define WAITL()  asm volatile("s_waitcnt lgkmcnt(0)" ::: "memory")

DEV void gload_lds16(const void* g, void* lds) {
  __builtin_amdgcn_global_load_lds(
      (const __attribute__((address_space(1))) void*)g,
      (__attribute__((address_space(3))) void*)lds, 16, 0, 0);
}

// ---------------- elementwise cast x -> bf16 ----------------
__global__ __launch_bounds__(256) void cast_to_bf16(const float* __restrict__ in,
                                                    bf16* __restrict__ out, int n8) {
  int i = blockIdx.x * 256 + threadIdx.x;
  if (i >= n8) return;
  float4 a0 = ((const float4*)in)[i * 2];
  float4 a1 = ((const float4*)in)[i * 2 + 1];
  bf16x8 o;
  o[0] = (bf16)a0.x; o[1] = (bf16)a0.y; o[2] = (bf16)a0.z; o[3] = (bf16)a0.w;
  o[4] = (bf16)a1.x; o[5] = (bf16)a1.y; o[6] = (bf16)a1.z; o[7] = (bf16)a1.w;
  ((bf16x8*)out)[i] = o;
}

// ---------------- W [K][N] f32 -> Wt [N][K] bf16 (LDS-tiled) ----------------
__global__ __launch_bounds__(256) void transpose_cast(const float* __restrict__ W,
                                                      bf16* __restrict__ Wt, int K, int N) {
  __shared__ bf16 tile[64][66];
  const int n0 = blockIdx.x * 64, k0 = blockIdx.y * 64;
  const int t = threadIdx.x;
#pragma unroll
  for (int it = 0; it < 16; ++it) {
    int c = it * 256 + t;
    int kr = c >> 6, nc = c & 63;
    tile[nc][kr] = (bf16)W[(size_t)(k0 + kr) * N + n0 + nc];
  }
  __syncthreads();
#pragma unroll
  for (int it = 0; it < 2; ++it) {
    int c = it * 256 + t;
    int nr = c >> 3, kg = (c & 7) * 8;
    bf16x8 v;
#pragma unroll
    for (int e = 0; e < 8; ++e) v[e] = tile[nr][kg + e];
    *(bf16x8*)(Wt + (size_t)(n0 + nr) * K + k0 + kg) = v;
  }
}

__global__ __launch_bounds__(256) void concat_bias(const float* __restrict__ bq,
                                                   const float* __restrict__ bk,
                                                   const float* __restrict__ bv,
                                                   float* __restrict__ o) {
  int i = blockIdx.x * 256 + threadIdx.x;
  if (i < 512) o[i] = bq[i];
  else if (i < 1024) o[i] = bk[i - 512];
  else if (i < 1536) o[i] = bv[i - 1024];
}

// ---------------- 256x256 GEMM: C[M][N] = A[M][K] @ Bt[N][K]^T + bias ----------
// 512 thr = 8 waves (2M x 4N), wave tile 128x64, BK=64.
// LDS 128KiB: buf{0,1} x {A-h0,A-h1,B-h0,B-h1} x 16KiB (128 rows x 64 cols bf16).
// Swizzle: in-row 16B-slot c holds global chunk c ^ (row&7); staged via
// inverse-swizzled GLOBAL source (LDS dest linear), read with the same XOR.
// Schedule per tile t (reading buf t&1): q=0 stages tile t+1 half-tiles 0,1;
// q=1 stages 2,3 (buf (t+1)&1 -- never the read buffer); q=3 drains vmcnt(0)
// before the boundary barrier. Per phase: {ds_read | stage | bar | lgkm0 |
// setprio1 16 MFMA setprio0 | bar}.
template <int RELU, int F32OUT>
__global__ __launch_bounds__(512, 1)
void gemm256(const bf16* __restrict__ A, const bf16* __restrict__ Bt,
             const float* __restrict__ bias, void* __restrict__ Cout,
             int M, int N, int K) {
  __shared__ bf16x8 lds8[8192];  // 128 KiB
  char* const LB = (char*)lds8;
  const int tid = threadIdx.x;
  const int w = tid >> 6, l = tid & 63;
  const int lr = l & 15, lg = l >> 4;
  const int wm = w >> 2, wn = w & 3;

  // XCD-aware bijective swizzle (nwg % 8 == 0 for all our grids)
  const int nwg = gridDim.x * gridDim.y;
  const int bid = blockIdx.y * gridDim.x + blockIdx.x;
  const int cpx = nwg >> 3;
  const int swzb = (bid & 7) * cpx + (bid >> 3);
  const int m0 = (swzb & 127) * 256;
  const int n0 = (swzb >> 7) * 256;

  const int NT = K >> 6;

  // staging: thread stages 16B slots tid and tid+512 of a half-tile.
  const int srow = tid >> 3;                         // 0..63 (second load: +64)
  const int scol = (((tid & 7) ^ (srow & 7)) << 3);  // inverse-swizzled col chunk

  // ds_read swizzled slot offsets (row&7 == lr&7 for all fragment rows)
  const int swz0 = ((lg ^ (lr & 7)) << 4);
  const int swz1 = (((4 + lg) ^ (lr & 7)) << 4);

  f32x4 acc[8][4];
#pragma unroll
  for (int i = 0; i < 8; ++i)
#pragma unroll
    for (int j = 0; j < 4; ++j) acc[i][j] = f32x4{0.f, 0.f, 0.f, 0.f};

  auto stage = [&](int ht) {
    const int th = ht >> 2;   // K-tile index
    const int h = ht & 1;     // half (128 rows)
    const bf16* g = ((ht & 2) ? (Bt + (size_t)(n0 + h * 128 + srow) * K)
                              : (A + (size_t)(m0 + h * 128 + srow) * K))
                    + th * 64 + scol;
    char* d = LB + (((th & 1) << 16) | ((ht & 3) << 14)) + tid * 16;
    gload_lds16(g, d);
    gload_lds16(g + (size_t)64 * K, d + 8192);
  };

  // prologue: tile 0 (4 half-tiles) -> buf 0, drain, barrier
#pragma unroll
  for (int p = 0; p < 4; ++p) stage(p);
  WAITV0();
  BAR();

  for (int t = 0; t < NT; ++t) {
    const char* pA = LB + ((t & 1) << 16) + (wm << 14) + lr * 128;
    const char* pB = LB + ((t & 1) << 16) + 32768 + ((wn >> 1) << 14) +
                     (((wn & 1) << 6) + lr) * 128;
    bf16x8 bq[4][2];
#pragma unroll
    for (int q = 0; q < 4; ++q) {
      // ds-load register subtile for this phase
      bf16x8 a0k0 = *(const bf16x8*)(pA + (2 * q) * 2048 + swz0);
      bf16x8 a0k1 = *(const bf16x8*)(pA + (2 * q) * 2048 + swz1);
      bf16x8 a1k0 = *(const bf16x8*)(pA + (2 * q + 1) * 2048 + swz0);
      bf16x8 a1k1 = *(const bf16x8*)(pA + (2 * q + 1) * 2048 + swz1);
      if (q == 0) {
#pragma unroll
        for (int n = 0; n < 4; ++n) {
          bq[n][0] = *(const bf16x8*)(pB + n * 2048 + swz0);
          bq[n][1] = *(const bf16x8*)(pB + n * 2048 + swz1);
        }
      }
      // stage tile t+1 only (2 half-tiles at q=0, 2 at q=1) -> buf (t+1)&1
      if (q < 2 && t + 1 < NT) {
        stage(4 * (t + 1) + 2 * q);
        stage(4 * (t + 1) + 2 * q + 1);
      }
      BAR();
      WAITL();
      __builtin_amdgcn_s_setprio(1);
#pragma unroll
      for (int n = 0; n < 4; ++n) {
        acc[2 * q][n]     = __builtin_amdgcn_mfma_f32_16x16x32_bf16(a0k0, bq[n][0], acc[2 * q][n], 0, 0, 0);
        acc[2 * q + 1][n] = __builtin_amdgcn_mfma_f32_16x16x32_bf16(a1k0, bq[n][0], acc[2 * q + 1][n], 0, 0, 0);
      }
#pragma unroll
      for (int n = 0; n < 4; ++n) {
        acc[2 * q][n]     = __builtin_amdgcn_mfma_f32_16x16x32_bf16(a0k1, bq[n][1], acc[2 * q][n], 0, 0, 0);
        acc[2 * q + 1][n] = __builtin_amdgcn_mfma_f32_16x16x32_bf16(a1k1, bq[n][1], acc[2 * q + 1][n], 0, 0, 0);
      }
      __builtin_amdgcn_s_setprio(0);
      if (q == 3 && t + 1 < NT) WAITV0();  // tile t+1 fully landed before reads
      BAR();
    }
  }

  // ---- epilogue ----
  if (!F32OUT) {
    // stage C tile (bf16) in LDS, then fully-coalesced 16B row stores
    bf16* cl = (bf16*)LB;  // [256][256]
#pragma unroll
    for (int n = 0; n < 4; ++n) {
      const int col = (wn << 6) + (n << 4) + lr;
      const float bv = bias[n0 + col];
#pragma unroll
      for (int m = 0; m < 8; ++m)
#pragma unroll
        for (int rg = 0; rg < 4; ++rg) {
          const int row = (wm << 7) + (m << 4) + (lg << 2) + rg;
          float v = acc[m][n][rg] + bv;
          if (RELU) v = fmaxf(v, 0.f);
          cl[row * 256 + col] = (bf16)v;
        }
    }
    WAITL();
    BAR();
    bf16* Cb = (bf16*)Cout;
#pragma unroll
    for (int it = 0; it < 16; ++it) {
      const int idx = it * 512 + tid;
      const int r = idx >> 5, ch = idx & 31;
      *(bf16x8*)(Cb + (size_t)(m0 + r) * N + n0 + (ch << 3)) =
          *(const bf16x8*)(cl + r * 256 + (ch << 3));
    }
  } else {
    // f32 stores: 16 lanes x 4B = 64B contiguous -> already line-coalesced
    float* Cf = (float*)Cout;
#pragma unroll
    for (int n = 0; n < 4; ++n) {
      const int col = n0 + (wn << 6) + (n << 4) + lr;
      const float bv = bias[col];
#pragma unroll
      for (int m = 0; m < 8; ++m)
#pragma unroll
        for (int rg = 0; rg < 4; ++rg) {
          const int row = m0 + (wm << 7) + (m << 4) + (lg << 2) + rg;
          float v = acc[m][n][rg] + bv;
          if (RELU) v = fmaxf(v, 0.f);
          Cf[(size_t)row * N + col] = v;
        }
    }
  }
}

// ---------------- V slice of qkv -> vt [B][512][4096] bf16 ----------------
__global__ __launch_bounds__(256) void transpose_v(const bf16* __restrict__ qkv,
                                                   bf16* __restrict__ vt) {
  __shared__ bf16 tile[64][66];
  const int s0 = blockIdx.x * 64, d0 = blockIdx.y * 64, b = blockIdx.z;
  const int t = threadIdx.x;
#pragma unroll
  for (int it = 0; it < 2; ++it) {
    int c = it * 256 + t;
    int r = c >> 3, g = (c & 7) * 8;
    bf16x8 v = *(const bf16x8*)(qkv + ((size_t)b * 4096 + s0 + r) * 1536 + 1024 + d0 + g);
#pragma unroll
    for (int e = 0; e < 8; ++e) tile[g + e][r] = v[e];
  }
  __syncthreads();
#pragma unroll
  for (int it = 0; it < 2; ++it) {
    int c = it * 256 + t;
    int dr = c >> 3, sg = (c & 7) * 8;
    bf16x8 v;
#pragma unroll
    for (int e = 0; e < 8; ++e) v[e] = tile[dr][sg + e];
    *(bf16x8*)(vt + ((size_t)b * 512 + d0 + dr) * 4096 + s0 + sg) = v;
  }
}

// ---------------- local attention ----------------
__global__ __launch_bounds__(256, 2)
void attn_local(const bf16* __restrict__ qkv, const bf16* __restrict__ vt,
                bf16* __restrict__ aout) {
  __shared__ bf16 P[4][16][200];
  const int qb = blockIdx.x, b = blockIdx.y;
  const int t = threadIdx.x, w = t >> 6, l = t & 63;
  const int lr = l & 15, lg = l >> 4;
  const int jlo = (qb == 0) ? 1 : 0;
  const int jhi = (qb == 63) ? 2 : 3;
  const size_t qrow = (size_t)b * 4096 + qb * 64 + w * 16;
  const bf16* qp = qkv + (qrow + lr) * 1536 + lg * 8;

  f32x4 S[3][4];
#pragma unroll
  for (int j = 0; j < 3; ++j)
#pragma unroll
    for (int n = 0; n < 4; ++n) S[j][n] = f32x4{0.f, 0.f, 0.f, 0.f};

  for (int kk = 0; kk < 16; ++kk) {
    bf16x8 aq = *(const bf16x8*)(qp + kk * 32);
#pragma unroll
    for (int j = 0; j < 3; ++j) {
      if (j < jlo || j >= jhi) continue;
      const bf16* kp = qkv + ((size_t)b * 4096 + (qb - 1 + j) * 64) * 1536 + 512;
#pragma unroll
      for (int n = 0; n < 4; ++n) {
        bf16x8 bk = *(const bf16x8*)(kp + (size_t)(n * 16 + lr) * 1536 + kk * 32 + lg * 8);
        S[j][n] = __builtin_amdgcn_mfma_f32_16x16x32_bf16(aq, bk, S[j][n], 0, 0, 0);
      }
    }
  }

  const float scale = 0.044194173824159216f;  // 1/sqrt(512)
  float mx[4] = {-3e38f, -3e38f, -3e38f, -3e38f};
#pragma unroll
  for (int j = 0; j < 3; ++j) {
    if (j < jlo || j >= jhi) continue;
#pragma unroll
    for (int n = 0; n < 4; ++n)
#pragma unroll
      for (int i = 0; i < 4; ++i) mx[i] = fmaxf(mx[i], S[j][n][i]);
  }
#pragma unroll
  for (int i = 0; i < 4; ++i) {
    mx[i] = fmaxf(mx[i], __shfl_xor(mx[i], 1));
    mx[i] = fmaxf(mx[i], __shfl_xor(mx[i], 2));
    mx[i] = fmaxf(mx[i], __shfl_xor(mx[i], 4));
    mx[i] = fmaxf(mx[i], __shfl_xor(mx[i], 8));
  }
  float sm[4] = {0.f, 0.f, 0.f, 0.f};
#pragma unroll
  for (int j = 0; j < 3; ++j) {
    if (j < jlo || j >= jhi) continue;
#pragma unroll
    for (int n = 0; n < 4; ++n)
#pragma unroll
      for (int i = 0; i < 4; ++i) {
        float p = __expf((S[j][n][i] - mx[i]) * scale);
        S[j][n][i] = p;
        sm[i] += p;
      }
  }
#pragma unroll
  for (int i = 0; i < 4; ++i) {
    sm[i] += __shfl_xor(sm[i], 1);
    sm[i] += __shfl_xor(sm[i], 2);
    sm[i] += __shfl_xor(sm[i], 4);
    sm[i] += __shfl_xor(sm[i], 8);
  }
#pragma unroll
  for (int j = 0; j < 3; ++j) {
    if (j < jlo || j >= jhi) continue;
#pragma unroll
    for (int n = 0; n < 4; ++n)
#pragma unroll
      for (int i = 0; i < 4; ++i)
        P[w][lg * 4 + i][j * 64 + n * 16 + lr] = (bf16)S[j][n][i];
  }
  float rinv[4];
#pragma unroll
  for (int i = 0; i < 4; ++i) rinv[i] = 1.f / sm[i];

  const bf16* vtb = vt + (size_t)b * 512 * 4096;
  const long scol = (long)qb * 64 - 64;

#pragma unroll
  for (int ch = 0; ch < 4; ++ch) {
    f32x4 O[8];
#pragma unroll
    for (int n = 0; n < 8; ++n) O[n] = f32x4{0.f, 0.f, 0.f, 0.f};
#pragma unroll
    for (int j = 0; j < 3; ++j) {
      if (j < jlo || j >= jhi) continue;
#pragma unroll
      for (int k2 = 0; k2 < 2; ++k2) {
        bf16x8 ap = *(const bf16x8*)&P[w][lr][j * 64 + k2 * 32 + lg * 8];
#pragma unroll
        for (int n = 0; n < 8; ++n) {
          const bf16* vp = vtb + (long)(ch * 128 + n * 16 + lr) * 4096 +
                           (scol + j * 64 + k2 * 32 + lg * 8);
          bf16x8 bv = *(const bf16x8*)vp;
          O[n] = __builtin_amdgcn_mfma_f32_16x16x32_bf16(ap, bv, O[n], 0, 0, 0);
        }
      }
    }
#pragma unroll
    for (int n = 0; n < 8; ++n)
#pragma unroll
      for (int rg = 0; rg < 4; ++rg) {
        size_t row = qrow + lg * 4 + rg;
        aout[row * 512 + ch * 128 + n * 16 + lr] = (bf16)(O[n][rg] * rinv[rg]);
      }
  }
}

// ---------------- LN1: out1 = LN(x + a) -> bf16 ----------------
__global__ __launch_bounds__(256) void ln_res1(const float* __restrict__ x,
                                               const bf16* __restrict__ a,
                                               const float* __restrict__ g,
                                               const float* __restrict__ be,
                                               bf16* __restrict__ out) {
  const int t = threadIdx.x, w = t >> 6, l = t & 63;
  const size_t row = (size_t)blockIdx.x * 4 + w;
  const float* xp = x + row * 512 + l * 8;
  float4 x0 = ((const float4*)xp)[0];
  float4 x1 = ((const float4*)xp)[1];
  bf16x8 av = *(const bf16x8*)(a + row * 512 + l * 8);
  float s[8] = {x0.x + (float)av[0], x0.y + (float)av[1], x0.z + (float)av[2], x0.w + (float)av[3],
                x1.x + (float)av[4], x1.y + (float)av[5], x1.z + (float)av[6], x1.w + (float)av[7]};
  float sum = 0.f;
#pragma unroll
  for (int i = 0; i < 8; ++i) sum += s[i];
#pragma unroll
  for (int m = 1; m <= 32; m <<= 1) sum += __shfl_xor(sum, m);
  const float mean = sum * (1.f / 512.f);
  float vs = 0.f;
#pragma unroll
  for (int i = 0; i < 8; ++i) { float d = s[i] - mean; vs += d * d; }
#pragma unroll
  for (int m = 1; m <= 32; m <<= 1) vs += __shfl_xor(vs, m);
  const float r = rsqrtf(vs * (1.f / 512.f) + 1e-6f);
  float4 g0 = ((const float4*)(g + l * 8))[0], g1 = ((const float4*)(g + l * 8))[1];
  float4 b0 = ((const float4*)(be + l * 8))[0], b1 = ((const float4*)(be + l * 8))[1];
  bf16x8 o;
  o[0] = (bf16)(g0.x * (s[0] - mean) * r + b0.x);
  o[1] = (bf16)(g0.y * (s[1] - mean) * r + b0.y);
  o[2] = (bf16)(g0.z * (s[2] - mean) * r + b0.z);
  o[3] = (bf16)(g0.w * (s[3] - mean) * r + b0.w);
  o[4] = (bf16)(g1.x * (s[4] - mean) * r + b1.x);
  o[5] = (bf16)(g1.y * (s[5] - mean) * r + b1.y);
  o[6] = (bf16)(g1.z * (s[6] - mean) * r + b1.z);
  o[7] = (bf16)(g1.w * (s[7] - mean) * r + b1.w);
  *(bf16x8*)(out + row * 512 + l * 8) = o;
}

// ---------------- LN2: out = LN(out1 + y), y in d_out (f32), in-place ----------------
__global__ __launch_bounds__(256) void ln_res2(const bf16* __restrict__ o1,
                                               float* __restrict__ y,
                                               const float* __restrict__ g,
                                               const float* __restrict__ be) {
  const int t = threadIdx.x, w = t >> 6, l = t & 63;
  const size_t row = (size_t)blockIdx.x * 4 + w;
  float* yp = y + row * 512 + l * 8;
  float4 y0 = ((const float4*)yp)[0];
  float4 y1 = ((const float4*)yp)[1];
  bf16x8 ov = *(const bf16x8*)(o1 + row * 512 + l * 8);
  float s[8] = {y0.x + (float)ov[0], y0.y + (float)ov[1], y0.z + (float)ov[2], y0.w + (float)ov[3],
                y1.x + (float)ov[4], y1.y + (float)ov[5], y1.z + (float)ov[6], y1.w + (float)ov[7]};
  float sum = 0.f;
#pragma unroll
  for (int i = 0; i < 8; ++i) sum += s[i];
#pragma unroll
  for (int m = 1; m <= 32; m <<= 1) sum += __shfl_xor(sum, m);
  const float mean = sum * (1.f / 512.f);
  float vs = 0.f;
#pragma unroll
  for (int i = 0; i < 8; ++i) { float d = s[i] - mean; vs += d * d; }
#pragma unroll
  for (int m = 1; m <= 32; m <<= 1) vs += __shfl_xor(vs, m);
  const float r = rsqrtf(vs * (1.f / 512.f) + 1e-6f);
  float4 g0 = ((const float4*)(g + l * 8))[0], g1 = ((const float4*)(g + l * 8))[1];
  float4 b0 = ((const float4*)(be + l * 8))[0], b1 = ((const float4*)(be + l * 8))[1];
  float4 r0, r1;
  r0.x = g0.x * (s[0] - mean) * r + b0.x;
  r0.y = g0.y * (s[1] - mean) * r + b0.y;
  r0.z = g0.z * (s[2] - mean) * r + b0.z;
  r0.w = g0.w * (s[3] - mean) * r + b0.w;
  r1.x = g1.x * (s[4] - mean) * r + b1.x;
  r1.y = g1.y * (s[5] - mean) * r + b1.y;
  r1.z = g1.z * (s[6] - mean) * r + b1.z;
  r1.w = g1.w * (s[7] - mean) * r + b1.w;
  ((float4*)yp)[0] = r0;
  ((float4*)yp)[1] = r1;
}

extern "C" void kernel_launch(void* const* d_in, const int* in_sizes, int n_in,
                              void* d_out, int out_size, void* d_ws, size_t ws_size,
                              hipStream_t stream) {
  const float* x   = (const float*)d_in[0];
  const float* Wq  = (const float*)d_in[1];
  const float* bq  = (const float*)d_in[2];
  const float* Wk  = (const float*)d_in[3];
  const float* bk  = (const float*)d_in[4];
  const float* Wv  = (const float*)d_in[5];
  const float* bv  = (const float*)d_in[6];
  const float* W1  = (const float*)d_in[7];
  const float* b1  = (const float*)d_in[8];
  const float* W2  = (const float*)d_in[9];
  const float* b2  = (const float*)d_in[10];
  const float* g1  = (const float*)d_in[11];
  const float* be1 = (const float*)d_in[12];
  const float* g2  = (const float*)d_in[13];
  const float* be2 = (const float*)d_in[14];
  float* out = (float*)d_out;

  char* ws = (char*)d_ws;
  // layout (bytes):
  bf16*  WqkvT = (bf16*)(ws + 0);          // [1536][512]      1,572,864
  bf16*  W1T   = (bf16*)(ws + 1572864);    // [2048][512]      2,097,152
  bf16*  W2T   = (bf16*)(ws + 3670016);    // [512][2048]      2,097,152
  float* bqkv  = (float*)(ws + 5767168);   // [1536]           6,144
  bf16*  xb    = (bf16*)(ws + 6291456);    // [32768][512]     33,554,432  (reused as attn out)
  bf16*  out1  = (bf16*)(ws + 39845888);   // [32768][512]     33,554,432
  bf16*  qkv   = (bf16*)(ws + 73400320);   // [32768][1536]    100,663,296
  bf16*  vtb   = (bf16*)(ws + 174063616);  // [8][512][4096]   33,554,432  -> end 207,618,048
  bf16*  a_    = xb;
  // h [32768][2048] bf16 = 134,217,728 B reuses qkv AND vtb regions (both dead
  // by FFN1 time): 73,400,320 + 134,217,728 = 207,618,048 <= ws end.
  bf16*  h     = qkv;

  cast_to_bf16<<<8192, 256, 0, stream>>>(x, xb, 2097152);
  transpose_cast<<<dim3(8, 8), 256, 0, stream>>>(Wq, WqkvT, 512, 512);
  transpose_cast<<<dim3(8, 8), 256, 0, stream>>>(Wk, WqkvT + 262144, 512, 512);
  transpose_cast<<<dim3(8, 8), 256, 0, stream>>>(Wv, WqkvT + 524288, 512, 512);
  transpose_cast<<<dim3(32, 8), 256, 0, stream>>>(W1, W1T, 512, 2048);
  transpose_cast<<<dim3(8, 32), 256, 0, stream>>>(W2, W2T, 2048, 512);
  concat_bias<<<6, 256, 0, stream>>>(bq, bk, bv, bqkv);

  gemm256<0, 0><<<dim3(128, 6), 512, 0, stream>>>(xb, WqkvT, bqkv, qkv, 32768, 1536, 512);
  transpose_v<<<dim3(64, 8, 8), 256, 0, stream>>>(qkv, vtb);
  attn_local<<<dim3(64, 8), 256, 0, stream>>>(qkv, vtb, a_);
  ln_res1<<<8192, 256, 0, stream>>>(x, a_, g1, be1, out1);
  gemm256<1, 0><<<dim3(128, 8), 512, 0, stream>>>(out1, W1T, b1, h, 32768, 2048, 512);
  gemm256<0, 1><<<dim3(128, 2), 512, 0, stream>>>(h, W2T, b2, out, 32768, 512, 2048);
  ln_res2<<<8192, 256, 0, stream>>>(out1, out, g2, be2);
}